// Round 5
// baseline (9.903 us; speedup 1.0000x reference)
//
#include <hip/hip_runtime.h>

#define NQ  10
#define BLK 256

// Closed form:
//   psi = (⊗_j G_j) · D · (⊗_j w_j)
//     w_j = H · R_j · rx(x_j*fm) |0>          (2-vector)
//     D   = diag Π_e e^{-i th_e z_e z_{e+1}}  (RXX chain in X basis)
//     G_j = Rf_j · H
//   <Z_j> = gam_j * d_j + 2 Re[ del_j * conj(w_j0) w_j1 * L_j * R_j ]
//     d_j = |w_j0|^2 - |w_j1|^2
//     L_j = cos(2 th_{j-1}) + i sin(2 th_{j-1}) d_{j-1}   (1 for j=0)
//     R_j = cos(2 th_j)     + i sin(2 th_j)     d_{j+1}   (1 for j=9)
//   out  = sum_j dk_j <Z_j> + bias
__global__ __launch_bounds__(BLK) void qnn_kernel(
    const float* __restrict__ x,      // (B, NQ)
    const float* __restrict__ fminp,  // (1,)
    const float* __restrict__ qw,     // (69,)
    const float* __restrict__ dk,     // (NQ,)
    const float* __restrict__ db,     // (1,)
    float* __restrict__ out,          // (B,)
    int B)
{
    __shared__ float P[80];                    // P_j = H * R_j (8 floats/qubit)
    __shared__ float g[10], dr_[10], di_[10];  // dk_j*gamma, dk_j*delta
    __shared__ float Tc[11], Ts[11];           // padded edge table cos/sin(2 th)

    const int t = threadIdx.x;
    const int b = blockIdx.x * BLK + t;
    const bool act = (b < B);
    const float is2 = 0.70710678118654752440f;

    // ---- issue per-thread input loads FIRST (overlap HBM latency w/ prelude) ----
    float xv[NQ];
    float fm = 0.0f, bias = 0.0f;
    if (act) {
        const float* xb = x + b * NQ;           // 40 B row, 8 B aligned
        #pragma unroll
        for (int k = 0; k < 5; ++k) {
            const float2 v = *reinterpret_cast<const float2*>(xb + 2 * k);
            xv[2*k] = v.x; xv[2*k + 1] = v.y;
        }
        fm   = fminp[0];
        bias = db[0];
    }

    // ---- per-block coefficient prelude (fast sincos; args are ~0.1) ----
    if (t < 10) {
        const float th = qw[3*t], ph = qw[3*t+1], al = qw[3*t+2];
        float st, ct, sa, ca, sp, cp;
        __sincosf(th, &st, &ct); __sincosf(al, &sa, &ca); __sincosf(ph, &sp, &cp);
        const float ss = st * sa;
        const float m00r = ct,    m00i = -st*ca, m01r = -ss*sp, m01i = -ss*cp;
        const float m10r = ss*sp, m10i = -ss*cp, m11r = ct,     m11i =  st*ca;
        float* p = P + 8*t;
        p[0] = (m00r+m10r)*is2; p[1] = (m00i+m10i)*is2;
        p[2] = (m01r+m11r)*is2; p[3] = (m01i+m11i)*is2;
        p[4] = (m00r-m10r)*is2; p[5] = (m00i-m10i)*is2;
        p[6] = (m01r-m11r)*is2; p[7] = (m01i-m11i)*is2;
    } else if (t < 20) {
        const int j = t - 10;
        const float th = qw[39+3*j], ph = qw[39+3*j+1], al = qw[39+3*j+2];
        float st, ct, sa, ca, sp, cp;
        __sincosf(th, &st, &ct); __sincosf(al, &sa, &ca); __sincosf(ph, &sp, &cp);
        const float ss = st * sa;
        const float m00r = ct,    m00i = -st*ca, m01r = -ss*sp, m01i = -ss*cp;
        const float m10r = ss*sp, m10i = -ss*cp, m11r = ct,     m11i =  st*ca;
        const float G00r=(m00r+m01r)*is2, G00i=(m00i+m01i)*is2;
        const float G01r=(m00r-m01r)*is2, G01i=(m00i-m01i)*is2;
        const float G10r=(m10r+m11r)*is2, G10i=(m10i+m11i)*is2;
        const float G11r=(m10r-m11r)*is2, G11i=(m10i-m11i)*is2;
        const float gam = G00r*G00r + G00i*G00i - G10r*G10r - G10i*G10i;
        const float der = G00r*G01r + G00i*G01i - (G10r*G11r + G10i*G11i);
        const float dei = G00r*G01i - G00i*G01r - (G10r*G11i - G10i*G11r);
        const float dkj = dk[j];
        g[j]   = dkj * gam;
        dr_[j] = dkj * der;
        di_[j] = dkj * dei;
    } else if (t < 29) {
        const int k = t - 19;                       // k = 1..9, edge k-1
        float s, c; __sincosf(2.0f * qw[30 + k - 1], &s, &c);
        Tc[k] = c; Ts[k] = s;
    } else if (t == 29) {
        Tc[0] = 1.0f; Ts[0] = 0.0f; Tc[10] = 1.0f; Ts[10] = 0.0f;
    }
    __syncthreads();

    if (!act) return;

    float d[NQ], mr[NQ], mi[NQ];
    #pragma unroll
    for (int j = 0; j < NQ; ++j) {
        const float a = 0.5f * fm * xv[j];
        const float s = __sinf(a), c = __cosf(a);
        const float* p = P + 8*j;
        const float w0r = p[0]*c + p[3]*s;
        const float w0i = p[1]*c - p[2]*s;
        const float w1r = p[4]*c + p[7]*s;
        const float w1i = p[5]*c - p[6]*s;
        d[j]  = (w0r*w0r + w0i*w0i) - (w1r*w1r + w1i*w1i);
        mr[j] = w0r*w1r + w0i*w1i;
        mi[j] = w0r*w1i - w0i*w1r;
    }

    float acc = 0.0f;
    #pragma unroll
    for (int j = 0; j < NQ; ++j) {
        const float dL = (j == 0)      ? 0.0f : d[j == 0 ? 0 : j - 1];
        const float dR = (j == NQ - 1) ? 0.0f : d[j == NQ - 1 ? NQ - 1 : j + 1];
        const float Lr = Tc[j],     Li = Ts[j]     * dL;
        const float Rr = Tc[j + 1], Ri = Ts[j + 1] * dR;
        const float LRr = Lr*Rr - Li*Ri;
        const float LRi = Lr*Ri + Li*Rr;
        const float Yr = mr[j]*LRr - mi[j]*LRi;
        const float Yi = mr[j]*LRi + mi[j]*LRr;
        acc += g[j]*d[j] + 2.0f*(dr_[j]*Yr - di_[j]*Yi);
    }
    out[b] = acc + bias;
}

extern "C" void kernel_launch(void* const* d_in, const int* in_sizes, int n_in,
                              void* d_out, int out_size, void* d_ws, size_t ws_size,
                              hipStream_t stream) {
    const float* x    = (const float*)d_in[0];
    const float* fmin = (const float*)d_in[1];
    const float* qw   = (const float*)d_in[2];
    const float* dk   = (const float*)d_in[3];
    const float* db   = (const float*)d_in[4];
    float* out = (float*)d_out;
    const int B = in_sizes[0] / NQ;   // 8192

    qnn_kernel<<<(B + BLK - 1) / BLK, BLK, 0, stream>>>(
        x, fmin, qw, dk, db, out, B);
}